// Round 1
// baseline (1085.024 us; speedup 1.0000x reference)
//
#include <hip/hip_runtime.h>
#include <math.h>

#define NUM_TOK   2048
#define HDIM      1024
#define IDIM      2048
#define NEXP      8
#define TILE      128
#define BK        16
#define MAX_ROWS  5120   // 4096 slots + 8 experts * 127 pad, rounded to 40 tiles
#define NTILES_M  40

// workspace layout (bytes)
#define OFF_IDX    0          // int   topk_idx[4096]
#define OFF_RW     16384      // float rw[4096]
#define OFF_CNT    32768      // int   counts[8], cursor[8]
#define OFF_SEG    32832      // int   seg_start[9]
#define OFF_ROWS   32896      // int   row_slot[5120]
#define OFF_ACT    65536      // float act[5120][2048]  (~42 MB)

__global__ void k_init(float* __restrict__ out, int* __restrict__ cnt,
                       int* __restrict__ rows) {
  int i = blockIdx.x * blockDim.x + threadIdx.x;   // 2048*256 = 524288 threads
  ((float4*)out)[i] = make_float4(0.f, 0.f, 0.f, 0.f);  // 2,097,152 floats exactly
  if (i < 16) cnt[i] = 0;
  if (i < MAX_ROWS) rows[i] = -1;
}

__global__ void k_router(const float* __restrict__ x, const float* __restrict__ wg,
                         int* __restrict__ idx, float* __restrict__ rw,
                         int* __restrict__ cnt) {
  const int wave = threadIdx.x >> 6;
  const int lane = threadIdx.x & 63;
  const int t = blockIdx.x * 4 + wave;   // one wave per token
  float acc[8];
#pragma unroll
  for (int q = 0; q < 8; ++q) acc[q] = 0.f;
  const float* xr = x + (size_t)t * HDIM;
#pragma unroll
  for (int j = 0; j < 16; ++j) {
    const int h = lane + (j << 6);
    const float xv = xr[h];
    const float4 w0 = *(const float4*)(wg + h * 8);
    const float4 w1 = *(const float4*)(wg + h * 8 + 4);
    acc[0] = fmaf(xv, w0.x, acc[0]); acc[1] = fmaf(xv, w0.y, acc[1]);
    acc[2] = fmaf(xv, w0.z, acc[2]); acc[3] = fmaf(xv, w0.w, acc[3]);
    acc[4] = fmaf(xv, w1.x, acc[4]); acc[5] = fmaf(xv, w1.y, acc[5]);
    acc[6] = fmaf(xv, w1.z, acc[6]); acc[7] = fmaf(xv, w1.w, acc[7]);
  }
#pragma unroll
  for (int q = 0; q < 8; ++q) {
#pragma unroll
    for (int off = 32; off >= 1; off >>= 1)
      acc[q] += __shfl_xor(acc[q], off, 64);
  }
  if (lane == 0) {
    int i0 = 0; float v0 = acc[0];
#pragma unroll
    for (int q = 1; q < 8; ++q)
      if (acc[q] > v0) { v0 = acc[q]; i0 = q; }   // ties -> lowest index, like top_k
    int i1 = -1; float v1 = -3.4e38f;
#pragma unroll
    for (int q = 0; q < 8; ++q)
      if (q != i0 && acc[q] > v1) { v1 = acc[q]; i1 = q; }
    const float e1 = expf(v1 - v0);
    const float inv = 1.f / (1.f + e1);
    idx[2 * t]     = i0;
    idx[2 * t + 1] = i1;
    rw[2 * t]      = inv;        // softmax([v0,v1]) with v0 >= v1
    rw[2 * t + 1]  = e1 * inv;
    atomicAdd(&cnt[i0], 1);
    atomicAdd(&cnt[i1], 1);
  }
}

__global__ void k_seg(const int* __restrict__ cnt, int* __restrict__ seg) {
  if (threadIdx.x == 0 && blockIdx.x == 0) {
    int s = 0;
    for (int q = 0; q < NEXP; ++q) {
      seg[q] = s;
      s += ((cnt[q] + TILE - 1) / TILE) * TILE;  // 128-aligned segments
    }
    seg[NEXP] = s;
  }
}

__global__ void k_scatter(const int* __restrict__ idx, const int* __restrict__ seg,
                          int* __restrict__ cursor, int* __restrict__ rows) {
  const int t = blockIdx.x * blockDim.x + threadIdx.x;
  if (t < NUM_TOK) {
#pragma unroll
    for (int k = 0; k < 2; ++k) {
      const int slot = 2 * t + k;
      const int e = idx[slot];
      const int p = atomicAdd(&cursor[e], 1);
      rows[seg[e] + p] = slot;
    }
  }
}

// ---- grouped GEMM 1: act = silu(x@W1) * (x@W3), gathered rows ----
__launch_bounds__(256, 2)
__global__ void k_gemm1(const float* __restrict__ x, const float* __restrict__ W1,
                        const float* __restrict__ W3, const int* __restrict__ seg,
                        const int* __restrict__ rows, float* __restrict__ act) {
  __shared__ float As[BK][TILE + 4];
  __shared__ float B1s[BK][16 * 12];   // 8-float groups, group stride 12 (2-way banks)
  __shared__ float B2s[BK][16 * 12];
  __shared__ int s_tok[TILE];
  __shared__ int s_seg[NEXP + 1];
  const int tid = threadIdx.x;
  if (tid < NEXP + 1) s_seg[tid] = seg[tid];
  __syncthreads();
  const int m0 = blockIdx.x * TILE;
  if (m0 >= s_seg[NEXP]) return;
  int e = 0;
#pragma unroll
  for (int q = 1; q < NEXP; ++q) if (m0 >= s_seg[q]) e = q;
  const int n0 = blockIdx.y * TILE;
  if (tid < TILE) {
    const int s = rows[m0 + tid];
    s_tok[tid] = (s >= 0) ? (s >> 1) : -1;
  }
  __syncthreads();
  const int ar = tid & (TILE - 1);
  const int ak = (tid >> 7) << 3;          // 0 or 8
  const int atok = s_tok[ar];
  const int bk = tid >> 4;                 // 0..15
  const int bg = tid & 15;                 // B col group 0..15 (8 cols each)
  const int ty = tid >> 4, tx = tid & 15;
  const size_t xoff = (size_t)(atok < 0 ? 0 : atok) * HDIM + ak;
  const float* __restrict__ b1base = W1 + (size_t)e * HDIM * IDIM + n0 + bg * 8;
  const float* __restrict__ b2base = W3 + (size_t)e * HDIM * IDIM + n0 + bg * 8;
  float accU[8][8], accG[8][8];
#pragma unroll
  for (int i = 0; i < 8; ++i)
#pragma unroll
    for (int j = 0; j < 8; ++j) { accU[i][j] = 0.f; accG[i][j] = 0.f; }

  for (int k0 = 0; k0 < HDIM; k0 += BK) {
    float4 av0 = *(const float4*)(x + xoff + k0);
    float4 av1 = *(const float4*)(x + xoff + k0 + 4);
    if (atok < 0) { av0 = make_float4(0,0,0,0); av1 = make_float4(0,0,0,0); }
    const float* bp1 = b1base + (size_t)(k0 + bk) * IDIM;
    const float* bp2 = b2base + (size_t)(k0 + bk) * IDIM;
    const float4 b10 = *(const float4*)bp1;
    const float4 b11 = *(const float4*)(bp1 + 4);
    const float4 b20 = *(const float4*)bp2;
    const float4 b21 = *(const float4*)(bp2 + 4);
    __syncthreads();
    As[ak + 0][ar] = av0.x; As[ak + 1][ar] = av0.y;
    As[ak + 2][ar] = av0.z; As[ak + 3][ar] = av0.w;
    As[ak + 4][ar] = av1.x; As[ak + 5][ar] = av1.y;
    As[ak + 6][ar] = av1.z; As[ak + 7][ar] = av1.w;
    *(float4*)&B1s[bk][bg * 12]     = b10;
    *(float4*)&B1s[bk][bg * 12 + 4] = b11;
    *(float4*)&B2s[bk][bg * 12]     = b20;
    *(float4*)&B2s[bk][bg * 12 + 4] = b21;
    __syncthreads();
#pragma unroll
    for (int k = 0; k < BK; ++k) {
      const float4 A0 = *(const float4*)&As[k][ty << 3];
      const float4 A1 = *(const float4*)&As[k][(ty << 3) + 4];
      const float4 U0 = *(const float4*)&B1s[k][tx * 12];
      const float4 U1 = *(const float4*)&B1s[k][tx * 12 + 4];
      const float4 G0 = *(const float4*)&B2s[k][tx * 12];
      const float4 G1 = *(const float4*)&B2s[k][tx * 12 + 4];
      const float a[8]  = {A0.x, A0.y, A0.z, A0.w, A1.x, A1.y, A1.z, A1.w};
      const float bu[8] = {U0.x, U0.y, U0.z, U0.w, U1.x, U1.y, U1.z, U1.w};
      const float bv[8] = {G0.x, G0.y, G0.z, G0.w, G1.x, G1.y, G1.z, G1.w};
#pragma unroll
      for (int i = 0; i < 8; ++i)
#pragma unroll
        for (int j = 0; j < 8; ++j) {
          accU[i][j] = fmaf(a[i], bu[j], accU[i][j]);
          accG[i][j] = fmaf(a[i], bv[j], accG[i][j]);
        }
    }
  }
#pragma unroll
  for (int i = 0; i < 8; ++i) {
    float ov[8];
#pragma unroll
    for (int j = 0; j < 8; ++j) {
      const float u = accU[i][j];
      const float s = u / (1.f + expf(-u));   // silu
      ov[j] = s * accG[i][j];
    }
    float* ap = act + (size_t)(m0 + (ty << 3) + i) * IDIM + n0 + (tx << 3);
    *(float4*)&ap[0] = make_float4(ov[0], ov[1], ov[2], ov[3]);
    *(float4*)&ap[4] = make_float4(ov[4], ov[5], ov[6], ov[7]);
  }
}

// ---- grouped GEMM 2: out[token] += w_slot * (act_row @ W2[e]) ----
__launch_bounds__(256, 2)
__global__ void k_gemm2(const float* __restrict__ act, const float* __restrict__ W2,
                        const int* __restrict__ seg, const int* __restrict__ rows,
                        const float* __restrict__ rw, float* __restrict__ out) {
  __shared__ float As[BK][TILE + 4];
  __shared__ float Bs[BK][16 * 12];
  __shared__ int s_slot[TILE];
  __shared__ float s_w[TILE];
  __shared__ int s_seg[NEXP + 1];
  const int tid = threadIdx.x;
  if (tid < NEXP + 1) s_seg[tid] = seg[tid];
  __syncthreads();
  const int m0 = blockIdx.x * TILE;
  if (m0 >= s_seg[NEXP]) return;
  int e = 0;
#pragma unroll
  for (int q = 1; q < NEXP; ++q) if (m0 >= s_seg[q]) e = q;
  const int n0 = blockIdx.y * TILE;
  if (tid < TILE) {
    const int s = rows[m0 + tid];
    s_slot[tid] = s;
    s_w[tid] = (s >= 0) ? rw[s] : 0.f;
  }
  __syncthreads();
  const int ar = tid & (TILE - 1);
  const int ak = (tid >> 7) << 3;
  const int bk = tid >> 4;
  const int bg = tid & 15;
  const int ty = tid >> 4, tx = tid & 15;
  const float* __restrict__ abase = act + (size_t)(m0 + ar) * IDIM + ak;
  const float* __restrict__ bbase = W2 + (size_t)e * IDIM * HDIM + n0 + bg * 8;
  float acc[8][8];
#pragma unroll
  for (int i = 0; i < 8; ++i)
#pragma unroll
    for (int j = 0; j < 8; ++j) acc[i][j] = 0.f;

  for (int k0 = 0; k0 < IDIM; k0 += BK) {
    const float4 av0 = *(const float4*)(abase + k0);
    const float4 av1 = *(const float4*)(abase + k0 + 4);
    const float* bp = bbase + (size_t)(k0 + bk) * HDIM;
    const float4 bv0 = *(const float4*)bp;
    const float4 bv1 = *(const float4*)(bp + 4);
    __syncthreads();
    As[ak + 0][ar] = av0.x; As[ak + 1][ar] = av0.y;
    As[ak + 2][ar] = av0.z; As[ak + 3][ar] = av0.w;
    As[ak + 4][ar] = av1.x; As[ak + 5][ar] = av1.y;
    As[ak + 6][ar] = av1.z; As[ak + 7][ar] = av1.w;
    *(float4*)&Bs[bk][bg * 12]     = bv0;
    *(float4*)&Bs[bk][bg * 12 + 4] = bv1;
    __syncthreads();
#pragma unroll
    for (int k = 0; k < BK; ++k) {
      const float4 A0 = *(const float4*)&As[k][ty << 3];
      const float4 A1 = *(const float4*)&As[k][(ty << 3) + 4];
      const float4 B0 = *(const float4*)&Bs[k][tx * 12];
      const float4 B1 = *(const float4*)&Bs[k][tx * 12 + 4];
      const float a[8] = {A0.x, A0.y, A0.z, A0.w, A1.x, A1.y, A1.z, A1.w};
      const float b[8] = {B0.x, B0.y, B0.z, B0.w, B1.x, B1.y, B1.z, B1.w};
#pragma unroll
      for (int i = 0; i < 8; ++i)
#pragma unroll
        for (int j = 0; j < 8; ++j)
          acc[i][j] = fmaf(a[i], b[j], acc[i][j]);
    }
  }
#pragma unroll
  for (int i = 0; i < 8; ++i) {
    const int rr = (ty << 3) + i;
    const int s = s_slot[rr];
    if (s >= 0) {
      const int t = s >> 1;
      const float w = s_w[rr];
      float* op = out + (size_t)t * HDIM + n0 + (tx << 3);
#pragma unroll
      for (int j = 0; j < 8; ++j)
        atomicAdd(op + j, acc[i][j] * w);
    }
  }
}

extern "C" void kernel_launch(void* const* d_in, const int* in_sizes, int n_in,
                              void* d_out, int out_size, void* d_ws, size_t ws_size,
                              hipStream_t stream) {
  const float* x  = (const float*)d_in[0];
  const float* Wg = (const float*)d_in[1];
  const float* W1 = (const float*)d_in[2];
  const float* W2 = (const float*)d_in[3];   // down (E, I, H)
  const float* W3 = (const float*)d_in[4];   // gate (E, H, I)
  float* out = (float*)d_out;
  char* ws = (char*)d_ws;
  int*   idx  = (int*)(ws + OFF_IDX);
  float* rw   = (float*)(ws + OFF_RW);
  int*   cnt  = (int*)(ws + OFF_CNT);    // counts[8] then cursor[8]
  int*   seg  = (int*)(ws + OFF_SEG);
  int*   rows = (int*)(ws + OFF_ROWS);
  float* act  = (float*)(ws + OFF_ACT);

  k_init<<<2048, 256, 0, stream>>>(out, cnt, rows);
  k_router<<<NUM_TOK / 4, 256, 0, stream>>>(x, Wg, idx, rw, cnt);
  k_seg<<<1, 64, 0, stream>>>(cnt, seg);
  k_scatter<<<NUM_TOK / 256, 256, 0, stream>>>(idx, seg, cnt + 8, rows);
  k_gemm1<<<dim3(NTILES_M, IDIM / TILE), 256, 0, stream>>>(x, W1, W3, seg, rows, act);
  k_gemm2<<<dim3(NTILES_M, HDIM / TILE), 256, 0, stream>>>(act, W2, seg, rows, rw, out);
}

// Round 2
// 263.626 us; speedup vs baseline: 4.1158x; 4.1158x over previous
//
#include <hip/hip_runtime.h>
#include <math.h>

#define NUM_TOK 2048
#define HDIM 1024
#define IDIM 2048
#define NEXP 8
#define MAX_ROWS 5120
#define NTM 40

typedef __attribute__((ext_vector_type(8))) short bf16x8;
typedef __attribute__((ext_vector_type(4))) float f32x4;

// ---- workspace offsets (bytes) ----
#define OFF_IDX   0u
#define OFF_RW    16384u
#define OFF_CNT   32768u
#define OFF_SEG   32832u
#define OFF_ROWS  33024u
#define OFF_POS   53504u
#define OFF_XB    131072u
#define OFF_W1T   8388608u
#define OFF_W3T   41943040u
#define OFF_W2T   75497472u
#define OFF_ACT   109051904u
#define OFF_SO    8388608u   /* aliases W1T (dead by the time gemm2 runs) */

__device__ __forceinline__ unsigned short f2bf(float f) {
  union { float f; unsigned u; } v; v.f = f;
  unsigned r = v.u + 0x7FFF + ((v.u >> 16) & 1);   // RNE
  return (unsigned short)(r >> 16);
}

__device__ __forceinline__ void gld16(const void* g, void* l) {
  __builtin_amdgcn_global_load_lds(
      (const __attribute__((address_space(1))) void*)g,
      (__attribute__((address_space(3))) void*)l, 16, 0, 0);
}

__global__ void k_init(int* __restrict__ cnt, int* __restrict__ rowsv) {
  const int i = blockIdx.x * blockDim.x + threadIdx.x;
  if (i < 16) cnt[i] = 0;
  if (i < MAX_ROWS) rowsv[i] = -1;
}

// transpose + fp32->bf16: src (R,C) per expert -> dst (C,R)
__global__ void k_wt(const float* __restrict__ src, unsigned short* __restrict__ dst,
                     int R, int C) {
  __shared__ __align__(16) unsigned short tile[64 * 72];
  const int tid = threadIdx.x;
  const size_t base = (size_t)blockIdx.z * R * C;
  const int r0 = blockIdx.y * 64, c0 = blockIdx.x * 64;
  const int c4 = (tid & 15) * 4;
#pragma unroll
  for (int j = 0; j < 4; ++j) {
    const int r = (tid >> 4) + j * 16;
    const float4 v = *(const float4*)(src + base + (size_t)(r0 + r) * C + c0 + c4);
    tile[(c4 + 0) * 72 + r] = f2bf(v.x);
    tile[(c4 + 1) * 72 + r] = f2bf(v.y);
    tile[(c4 + 2) * 72 + r] = f2bf(v.z);
    tile[(c4 + 3) * 72 + r] = f2bf(v.w);
  }
  __syncthreads();
  const int r8 = (tid & 7) * 8;
#pragma unroll
  for (int j = 0; j < 2; ++j) {
    const int c = (tid >> 3) + j * 32;
    const uint4 d = *(const uint4*)&tile[c * 72 + r8];
    *(uint4*)(dst + base + (size_t)(c0 + c) * R + r0 + r8) = d;
  }
}

__global__ void k_router(const float* __restrict__ x, const float* __restrict__ wg,
                         unsigned short* __restrict__ xb,
                         int* __restrict__ idx, float* __restrict__ rw,
                         int* __restrict__ cnt) {
  const int wave = threadIdx.x >> 6, lane = threadIdx.x & 63;
  const int t = blockIdx.x * 4 + wave;
  const float2* __restrict__ xr = (const float2*)(x + (size_t)t * HDIM);
  unsigned* __restrict__ xbr = (unsigned*)(xb + (size_t)t * HDIM);
  float acc[8];
#pragma unroll
  for (int q = 0; q < 8; ++q) acc[q] = 0.f;
#pragma unroll
  for (int j = 0; j < 8; ++j) {
    const int h2 = lane + (j << 6);
    const float2 v = xr[h2];
    const float* wrow = wg + (size_t)h2 * 16;
    const float4 a0 = *(const float4*)(wrow);
    const float4 a1 = *(const float4*)(wrow + 4);
    const float4 b0 = *(const float4*)(wrow + 8);
    const float4 b1 = *(const float4*)(wrow + 12);
    acc[0] = fmaf(v.x, a0.x, fmaf(v.y, b0.x, acc[0]));
    acc[1] = fmaf(v.x, a0.y, fmaf(v.y, b0.y, acc[1]));
    acc[2] = fmaf(v.x, a0.z, fmaf(v.y, b0.z, acc[2]));
    acc[3] = fmaf(v.x, a0.w, fmaf(v.y, b0.w, acc[3]));
    acc[4] = fmaf(v.x, a1.x, fmaf(v.y, b1.x, acc[4]));
    acc[5] = fmaf(v.x, a1.y, fmaf(v.y, b1.y, acc[5]));
    acc[6] = fmaf(v.x, a1.z, fmaf(v.y, b1.z, acc[6]));
    acc[7] = fmaf(v.x, a1.w, fmaf(v.y, b1.w, acc[7]));
    xbr[h2] = (unsigned)f2bf(v.x) | ((unsigned)f2bf(v.y) << 16);
  }
#pragma unroll
  for (int q = 0; q < 8; ++q) {
#pragma unroll
    for (int off = 32; off >= 1; off >>= 1)
      acc[q] += __shfl_xor(acc[q], off, 64);
  }
  if (lane == 0) {
    int i0 = 0; float v0 = acc[0];
#pragma unroll
    for (int q = 1; q < 8; ++q)
      if (acc[q] > v0) { v0 = acc[q]; i0 = q; }
    int i1 = -1; float v1 = -3.4e38f;
#pragma unroll
    for (int q = 0; q < 8; ++q)
      if (q != i0 && acc[q] > v1) { v1 = acc[q]; i1 = q; }
    const float e1 = expf(v1 - v0);
    const float inv = 1.f / (1.f + e1);
    idx[2 * t] = i0; idx[2 * t + 1] = i1;
    rw[2 * t] = inv; rw[2 * t + 1] = e1 * inv;
    atomicAdd(&cnt[i0], 1);
    atomicAdd(&cnt[i1], 1);
  }
}

__global__ void k_seg(const int* __restrict__ cnt, int* __restrict__ seg) {
  int s = 0;
  for (int q = 0; q < NEXP; ++q) {
    seg[q] = s;
    s += ((cnt[q] + 127) / 128) * 128;
  }
  seg[NEXP] = s;
}

__global__ void k_scatter(const int* __restrict__ idx, const int* __restrict__ seg,
                          int* __restrict__ cursor, int* __restrict__ rowsv,
                          int* __restrict__ pos) {
  const int t = blockIdx.x * blockDim.x + threadIdx.x;
  if (t < NUM_TOK) {
#pragma unroll
    for (int k = 0; k < 2; ++k) {
      const int slot = 2 * t + k;
      const int e = idx[slot];
      const int p = atomicAdd(&cursor[e], 1);
      const int rr = seg[e] + p;
      rowsv[rr] = slot;
      pos[slot] = rr;
    }
  }
}

// grouped GEMM1: act[row][i] = silu(x@W1) * (x@W3); B-tile = 64 W1T rows + 64 W3T rows
__launch_bounds__(256, 2)
__global__ void k_gemm1(const unsigned short* __restrict__ xb,
                        const unsigned short* __restrict__ W1T,
                        const unsigned short* __restrict__ W3T,
                        const int* __restrict__ seg, const int* __restrict__ rowsv,
                        unsigned short* __restrict__ act) {
  __shared__ __align__(16) unsigned short As[2][128 * 32];
  __shared__ __align__(16) unsigned short Bs[2][128 * 32];
  const int tid = threadIdx.x;
  const int w = tid >> 6, l = tid & 63;
  const int m0 = blockIdx.x * 128;
  const int total = seg[NEXP];
  if (m0 >= total) return;
  int e = 0;
#pragma unroll
  for (int q = 1; q < NEXP; ++q) if (m0 >= seg[q]) e = q;
  const int n0 = blockIdx.y * 64;

  size_t aOff[2], bOff[2];
#pragma unroll
  for (int q = 0; q < 2; ++q) {
    const int r = rowsv[m0 + w * 32 + q * 16 + (l >> 2)];
    const int tk = (r < 0) ? 0 : (r >> 1);
    aOff[q] = (size_t)tk * HDIM + (l & 3) * 8;
    bOff[q] = ((size_t)e * IDIM + n0 + (w & 1) * 32 + q * 16 + (l >> 2)) * HDIM + (l & 3) * 8;
  }
  const unsigned short* __restrict__ WT = (w < 2) ? W1T : W3T;

  f32x4 acc[2][8];
#pragma unroll
  for (int m = 0; m < 2; ++m)
#pragma unroll
    for (int nf = 0; nf < 8; ++nf) acc[m][nf] = (f32x4)0.f;

  auto stage = [&](int buf, int k0) {
#pragma unroll
    for (int q = 0; q < 2; ++q) {
      gld16(xb + aOff[q] + k0, &As[buf][(w * 32 + q * 16) * 32]);
      gld16(WT + bOff[q] + k0, &Bs[buf][(w * 32 + q * 16) * 32]);
    }
  };

  stage(0, 0);
  __syncthreads();
  const int arow = (w * 32 + (l & 15)) * 32 + (l >> 4) * 8;
  for (int t = 0; t < HDIM / 32; ++t) {
    const int cur = t & 1;
    if (t + 1 < HDIM / 32) stage(cur ^ 1, (t + 1) * 32);
    const bf16x8 a0 = *(const bf16x8*)&As[cur][arow];
    const bf16x8 a1 = *(const bf16x8*)&As[cur][arow + 16 * 32];
#pragma unroll
    for (int nf = 0; nf < 8; ++nf) {
      const bf16x8 b = *(const bf16x8*)&Bs[cur][(nf * 16 + (l & 15)) * 32 + (l >> 4) * 8];
      acc[0][nf] = __builtin_amdgcn_mfma_f32_16x16x32_bf16(a0, b, acc[0][nf], 0, 0, 0);
      acc[1][nf] = __builtin_amdgcn_mfma_f32_16x16x32_bf16(a1, b, acc[1][nf], 0, 0, 0);
    }
    __syncthreads();
  }
  const int rbase = m0 + w * 32 + (l >> 4) * 4;
  const int cbase = n0 + (l & 15);
#pragma unroll
  for (int m = 0; m < 2; ++m)
#pragma unroll
    for (int p = 0; p < 4; ++p) {
      const f32x4 up = acc[m][p];
      const f32x4 gt = acc[m][p + 4];
#pragma unroll
      for (int r = 0; r < 4; ++r) {
        const float u = up[r];
        const float s = (u / (1.f + expf(-u))) * gt[r];
        act[(size_t)(rbase + m * 16 + r) * IDIM + cbase + p * 16] = f2bf(s);
      }
    }
}

// grouped GEMM2: so[row][h] = act[row] @ W2T[e]  (fp32 per-slot partials)
__launch_bounds__(256, 2)
__global__ void k_gemm2(const unsigned short* __restrict__ act,
                        const unsigned short* __restrict__ W2T,
                        const int* __restrict__ seg,
                        float* __restrict__ so) {
  __shared__ __align__(16) unsigned short As[2][128 * 32];
  __shared__ __align__(16) unsigned short Bs[2][64 * 32];
  const int tid = threadIdx.x;
  const int w = tid >> 6, l = tid & 63;
  const int m0 = blockIdx.x * 128;
  const int total = seg[NEXP];
  if (m0 >= total) return;
  int e = 0;
#pragma unroll
  for (int q = 1; q < NEXP; ++q) if (m0 >= seg[q]) e = q;
  const int n0 = blockIdx.y * 64;
  size_t aOff[2];
#pragma unroll
  for (int q = 0; q < 2; ++q)
    aOff[q] = (size_t)(m0 + w * 32 + q * 16 + (l >> 2)) * IDIM + (l & 3) * 8;
  const size_t bOff = ((size_t)e * HDIM + n0 + w * 16 + (l >> 2)) * IDIM + (l & 3) * 8;

  f32x4 acc[2][4];
#pragma unroll
  for (int m = 0; m < 2; ++m)
#pragma unroll
    for (int nf = 0; nf < 4; ++nf) acc[m][nf] = (f32x4)0.f;

  auto stage = [&](int buf, int k0) {
#pragma unroll
    for (int q = 0; q < 2; ++q)
      gld16(act + aOff[q] + k0, &As[buf][(w * 32 + q * 16) * 32]);
    gld16(W2T + bOff + k0, &Bs[buf][(w * 16) * 32]);
  };

  stage(0, 0);
  __syncthreads();
  const int arow = (w * 32 + (l & 15)) * 32 + (l >> 4) * 8;
  for (int t = 0; t < IDIM / 32; ++t) {
    const int cur = t & 1;
    if (t + 1 < IDIM / 32) stage(cur ^ 1, (t + 1) * 32);
    const bf16x8 a0 = *(const bf16x8*)&As[cur][arow];
    const bf16x8 a1 = *(const bf16x8*)&As[cur][arow + 16 * 32];
#pragma unroll
    for (int nf = 0; nf < 4; ++nf) {
      const bf16x8 b = *(const bf16x8*)&Bs[cur][(nf * 16 + (l & 15)) * 32 + (l >> 4) * 8];
      acc[0][nf] = __builtin_amdgcn_mfma_f32_16x16x32_bf16(a0, b, acc[0][nf], 0, 0, 0);
      acc[1][nf] = __builtin_amdgcn_mfma_f32_16x16x32_bf16(a1, b, acc[1][nf], 0, 0, 0);
    }
    __syncthreads();
  }
  const int rbase = m0 + w * 32 + (l >> 4) * 4;
  const int cbase = n0 + (l & 15);
#pragma unroll
  for (int m = 0; m < 2; ++m)
#pragma unroll
    for (int nf = 0; nf < 4; ++nf)
#pragma unroll
      for (int r = 0; r < 4; ++r)
        so[(size_t)(rbase + m * 16 + r) * HDIM + cbase + nf * 16] = acc[m][nf][r];
}

__global__ void k_combine(const float* __restrict__ so, const int* __restrict__ pos,
                          const float* __restrict__ rw, float* __restrict__ out) {
  const int t = blockIdx.x, i = threadIdx.x;
  const int p0 = pos[2 * t], p1 = pos[2 * t + 1];
  const float w0 = rw[2 * t], w1 = rw[2 * t + 1];
  const float4 a = ((const float4*)(so + (size_t)p0 * HDIM))[i];
  const float4 b = ((const float4*)(so + (size_t)p1 * HDIM))[i];
  float4 o;
  o.x = w0 * a.x + w1 * b.x;
  o.y = w0 * a.y + w1 * b.y;
  o.z = w0 * a.z + w1 * b.z;
  o.w = w0 * a.w + w1 * b.w;
  ((float4*)(out + (size_t)t * HDIM))[i] = o;
}

extern "C" void kernel_launch(void* const* d_in, const int* in_sizes, int n_in,
                              void* d_out, int out_size, void* d_ws, size_t ws_size,
                              hipStream_t stream) {
  const float* x  = (const float*)d_in[0];
  const float* Wg = (const float*)d_in[1];
  const float* W1 = (const float*)d_in[2];
  const float* W2 = (const float*)d_in[3];   // (E, I, H)
  const float* W3 = (const float*)d_in[4];   // (E, H, I)
  float* out = (float*)d_out;
  char* ws = (char*)d_ws;
  int*   idx  = (int*)(ws + OFF_IDX);
  float* rw   = (float*)(ws + OFF_RW);
  int*   cnt  = (int*)(ws + OFF_CNT);
  int*   seg  = (int*)(ws + OFF_SEG);
  int*   rowsv= (int*)(ws + OFF_ROWS);
  int*   pos  = (int*)(ws + OFF_POS);
  unsigned short* xb  = (unsigned short*)(ws + OFF_XB);
  unsigned short* W1T = (unsigned short*)(ws + OFF_W1T);
  unsigned short* W3T = (unsigned short*)(ws + OFF_W3T);
  unsigned short* W2T = (unsigned short*)(ws + OFF_W2T);
  unsigned short* act = (unsigned short*)(ws + OFF_ACT);
  float* so = (float*)(ws + OFF_SO);

  k_init<<<20, 256, 0, stream>>>(cnt, rowsv);
  k_wt<<<dim3(IDIM / 64, HDIM / 64, NEXP), 256, 0, stream>>>(W1, W1T, HDIM, IDIM);
  k_wt<<<dim3(IDIM / 64, HDIM / 64, NEXP), 256, 0, stream>>>(W3, W3T, HDIM, IDIM);
  k_wt<<<dim3(HDIM / 64, IDIM / 64, NEXP), 256, 0, stream>>>(W2, W2T, IDIM, HDIM);
  k_router<<<NUM_TOK / 4, 256, 0, stream>>>(x, Wg, xb, idx, rw, cnt);
  k_seg<<<1, 1, 0, stream>>>(cnt, seg);
  k_scatter<<<NUM_TOK / 256, 256, 0, stream>>>(idx, seg, cnt + 8, rowsv, pos);
  k_gemm1<<<dim3(NTM, IDIM / 64), 256, 0, stream>>>(xb, W1T, W3T, seg, rowsv, act);
  k_gemm2<<<dim3(NTM, HDIM / 64), 256, 0, stream>>>(act, W2T, seg, so);
  k_combine<<<NUM_TOK, 256, 0, stream>>>(so, pos, rw, out);
}

// Round 3
// 250.770 us; speedup vs baseline: 4.3268x; 1.0513x over previous
//
#include <hip/hip_runtime.h>
#include <math.h>

#define NUM_TOK 2048
#define HDIM 1024
#define IDIM 2048
#define NEXP 8
#define MAX_ROWS 5120
#define NTM 40

typedef __attribute__((ext_vector_type(8))) short bf16x8;
typedef __attribute__((ext_vector_type(4))) float f32x4;

// ---- workspace offsets (bytes) ----
#define OFF_IDX   0u
#define OFF_RW    16384u
#define OFF_CNT   32768u
#define OFF_SEG   32832u
#define OFF_ROWS  33024u
#define OFF_POS   53504u
#define OFF_XB    131072u
#define OFF_W1T   8388608u
#define OFF_W3T   41943040u
#define OFF_W2T   75497472u
#define OFF_ACT   109051904u
#define OFF_SO    8388608u   /* aliases W1T (dead once gemm2 runs) */

__device__ __forceinline__ unsigned short f2bf(float f) {
  union { float f; unsigned u; } v; v.f = f;
  unsigned r = v.u + 0x7FFF + ((v.u >> 16) & 1);   // RNE
  return (unsigned short)(r >> 16);
}

__device__ __forceinline__ void gld16(const void* g, void* l) {
  __builtin_amdgcn_global_load_lds(
      (const __attribute__((address_space(1))) void*)g,
      (__attribute__((address_space(3))) void*)l, 16, 0, 0);
}

__global__ void k_init(int* __restrict__ cnt, int* __restrict__ rowsv) {
  const int i = blockIdx.x * blockDim.x + threadIdx.x;
  if (i < 16) cnt[i] = 0;
  if (i < MAX_ROWS) rowsv[i] = -1;
}

// transpose + fp32->bf16: src (R,C) per expert -> dst (C,R)
__global__ void k_wt(const float* __restrict__ src, unsigned short* __restrict__ dst,
                     int R, int C) {
  __shared__ __align__(16) unsigned short tile[64 * 72];
  const int tid = threadIdx.x;
  const size_t base = (size_t)blockIdx.z * R * C;
  const int r0 = blockIdx.y * 64, c0 = blockIdx.x * 64;
  const int c4 = (tid & 15) * 4;
#pragma unroll
  for (int j = 0; j < 4; ++j) {
    const int r = (tid >> 4) + j * 16;
    const float4 v = *(const float4*)(src + base + (size_t)(r0 + r) * C + c0 + c4);
    tile[(c4 + 0) * 72 + r] = f2bf(v.x);
    tile[(c4 + 1) * 72 + r] = f2bf(v.y);
    tile[(c4 + 2) * 72 + r] = f2bf(v.z);
    tile[(c4 + 3) * 72 + r] = f2bf(v.w);
  }
  __syncthreads();
  const int r8 = (tid & 7) * 8;
#pragma unroll
  for (int j = 0; j < 2; ++j) {
    const int c = (tid >> 3) + j * 32;
    const uint4 d = *(const uint4*)&tile[c * 72 + r8];
    *(uint4*)(dst + base + (size_t)(c0 + c) * R + r0 + r8) = d;
  }
}

__global__ void k_router(const float* __restrict__ x, const float* __restrict__ wg,
                         unsigned short* __restrict__ xb,
                         int* __restrict__ idx, float* __restrict__ rw,
                         int* __restrict__ cnt) {
  const int wave = threadIdx.x >> 6, lane = threadIdx.x & 63;
  const int t = blockIdx.x * 4 + wave;
  const float2* __restrict__ xr = (const float2*)(x + (size_t)t * HDIM);
  unsigned* __restrict__ xbr = (unsigned*)(xb + (size_t)t * HDIM);
  float acc[8];
#pragma unroll
  for (int q = 0; q < 8; ++q) acc[q] = 0.f;
#pragma unroll
  for (int j = 0; j < 8; ++j) {
    const int h2 = lane + (j << 6);
    const float2 v = xr[h2];
    const float* wrow = wg + (size_t)h2 * 16;
    const float4 a0 = *(const float4*)(wrow);
    const float4 a1 = *(const float4*)(wrow + 4);
    const float4 b0 = *(const float4*)(wrow + 8);
    const float4 b1 = *(const float4*)(wrow + 12);
    acc[0] = fmaf(v.x, a0.x, fmaf(v.y, b0.x, acc[0]));
    acc[1] = fmaf(v.x, a0.y, fmaf(v.y, b0.y, acc[1]));
    acc[2] = fmaf(v.x, a0.z, fmaf(v.y, b0.z, acc[2]));
    acc[3] = fmaf(v.x, a0.w, fmaf(v.y, b0.w, acc[3]));
    acc[4] = fmaf(v.x, a1.x, fmaf(v.y, b1.x, acc[4]));
    acc[5] = fmaf(v.x, a1.y, fmaf(v.y, b1.y, acc[5]));
    acc[6] = fmaf(v.x, a1.z, fmaf(v.y, b1.z, acc[6]));
    acc[7] = fmaf(v.x, a1.w, fmaf(v.y, b1.w, acc[7]));
    xbr[h2] = (unsigned)f2bf(v.x) | ((unsigned)f2bf(v.y) << 16);
  }
#pragma unroll
  for (int q = 0; q < 8; ++q) {
#pragma unroll
    for (int off = 32; off >= 1; off >>= 1)
      acc[q] += __shfl_xor(acc[q], off, 64);
  }
  if (lane == 0) {
    int i0 = 0; float v0 = acc[0];
#pragma unroll
    for (int q = 1; q < 8; ++q)
      if (acc[q] > v0) { v0 = acc[q]; i0 = q; }
    int i1 = -1; float v1 = -3.4e38f;
#pragma unroll
    for (int q = 0; q < 8; ++q)
      if (q != i0 && acc[q] > v1) { v1 = acc[q]; i1 = q; }
    const float e1 = expf(v1 - v0);
    const float inv = 1.f / (1.f + e1);
    idx[2 * t] = i0; idx[2 * t + 1] = i1;
    rw[2 * t] = inv; rw[2 * t + 1] = e1 * inv;
    atomicAdd(&cnt[i0], 1);
    atomicAdd(&cnt[i1], 1);
  }
}

__global__ void k_seg(const int* __restrict__ cnt, int* __restrict__ seg) {
  int s = 0;
  for (int q = 0; q < NEXP; ++q) {
    seg[q] = s;
    s += ((cnt[q] + 127) / 128) * 128;
  }
  seg[NEXP] = s;
}

__global__ void k_scatter(const int* __restrict__ idx, const int* __restrict__ seg,
                          int* __restrict__ cursor, int* __restrict__ rowsv,
                          int* __restrict__ pos) {
  const int t = blockIdx.x * blockDim.x + threadIdx.x;
  if (t < NUM_TOK) {
#pragma unroll
    for (int k = 0; k < 2; ++k) {
      const int slot = 2 * t + k;
      const int e = idx[slot];
      const int p = atomicAdd(&cursor[e], 1);
      const int rr = seg[e] + p;
      rowsv[rr] = slot;
      pos[slot] = rr;
    }
  }
}

// grouped GEMM1: act = silu(x@W1) * (x@W3); B-tile = 64 W1T rows + 64 W3T rows.
// LDS XOR-swizzled: physical 16B slot p at row r holds logical slot p^((r>>1)&3);
// achieved by pre-swizzling the global source column (linear global_load_lds dest)
// and XOR-ing the slot on ds_read.
__launch_bounds__(256, 2)
__global__ void k_gemm1(const unsigned short* __restrict__ xb,
                        const unsigned short* __restrict__ W1T,
                        const unsigned short* __restrict__ W3T,
                        const int* __restrict__ seg, const int* __restrict__ rowsv,
                        unsigned short* __restrict__ act) {
  __shared__ __align__(16) unsigned short As[2][128 * 32];
  __shared__ __align__(16) unsigned short Bs[2][128 * 32];
  const int tid = threadIdx.x;
  const int w = tid >> 6, l = tid & 63;
  const int m0 = blockIdx.y * 128;
  const int total = seg[NEXP];
  if (m0 >= total) return;
  int e = 0;
#pragma unroll
  for (int q = 1; q < NEXP; ++q) if (m0 >= seg[q]) e = q;
  const int n0 = blockIdx.x * 64;

  const int swzst = ((l & 3) ^ ((l >> 3) & 3)) * 8;   // staging source column (elems)
  size_t aOff[2], bOff[2];
#pragma unroll
  for (int q = 0; q < 2; ++q) {
    const int r = rowsv[m0 + w * 32 + q * 16 + (l >> 2)];
    const int tk = (r < 0) ? 0 : (r >> 1);
    aOff[q] = (size_t)tk * HDIM + swzst;
    bOff[q] = ((size_t)e * IDIM + n0 + (w & 1) * 32 + q * 16 + (l >> 2)) * HDIM + swzst;
  }
  const unsigned short* __restrict__ WT = (w < 2) ? W1T : W3T;

  f32x4 acc[2][8];
#pragma unroll
  for (int m = 0; m < 2; ++m)
#pragma unroll
    for (int nf = 0; nf < 8; ++nf) acc[m][nf] = (f32x4)0.f;

  auto stage = [&](int buf, int k0) {
#pragma unroll
    for (int q = 0; q < 2; ++q) {
      gld16(xb + aOff[q] + k0, &As[buf][(w * 32 + q * 16) * 32]);
      gld16(WT + bOff[q] + k0, &Bs[buf][(w * 32 + q * 16) * 32]);
    }
  };

  stage(0, 0);
  __syncthreads();
  const int rslot = ((l >> 4) ^ ((l >> 1) & 3)) * 8;  // swizzled read slot (elems)
  const int arow = (w * 32 + (l & 15)) * 32 + rslot;
  for (int t = 0; t < HDIM / 32; ++t) {
    const int cur = t & 1;
    if (t + 1 < HDIM / 32) stage(cur ^ 1, (t + 1) * 32);
    const bf16x8 a0 = *(const bf16x8*)&As[cur][arow];
    const bf16x8 a1 = *(const bf16x8*)&As[cur][arow + 16 * 32];
#pragma unroll
    for (int nf = 0; nf < 8; ++nf) {
      const bf16x8 b = *(const bf16x8*)&Bs[cur][(nf * 16 + (l & 15)) * 32 + rslot];
      acc[0][nf] = __builtin_amdgcn_mfma_f32_16x16x32_bf16(a0, b, acc[0][nf], 0, 0, 0);
      acc[1][nf] = __builtin_amdgcn_mfma_f32_16x16x32_bf16(a1, b, acc[1][nf], 0, 0, 0);
    }
    __syncthreads();
  }
  const int rbase = m0 + w * 32 + (l >> 4) * 4;
  const int cbase = n0 + (l & 15);
#pragma unroll
  for (int m = 0; m < 2; ++m)
#pragma unroll
    for (int p = 0; p < 4; ++p) {
      const f32x4 up = acc[m][p];
      const f32x4 gt = acc[m][p + 4];
#pragma unroll
      for (int r = 0; r < 4; ++r) {
        const float u = up[r];
        const float s = (u / (1.f + expf(-u))) * gt[r];
        act[(size_t)(rbase + m * 16 + r) * IDIM + cbase + p * 16] = f2bf(s);
      }
    }
}

// grouped GEMM2: so[row][h] = act[row] @ W2T[e]  (fp32 per-slot partials)
__launch_bounds__(256, 2)
__global__ void k_gemm2(const unsigned short* __restrict__ act,
                        const unsigned short* __restrict__ W2T,
                        const int* __restrict__ seg,
                        float* __restrict__ so) {
  __shared__ __align__(16) unsigned short As[2][128 * 32];
  __shared__ __align__(16) unsigned short Bs[2][64 * 32];
  const int tid = threadIdx.x;
  const int w = tid >> 6, l = tid & 63;
  const int m0 = blockIdx.y * 128;
  const int total = seg[NEXP];
  if (m0 >= total) return;
  int e = 0;
#pragma unroll
  for (int q = 1; q < NEXP; ++q) if (m0 >= seg[q]) e = q;
  const int n0 = blockIdx.x * 64;
  const int swzst = ((l & 3) ^ ((l >> 3) & 3)) * 8;
  size_t aOff[2];
#pragma unroll
  for (int q = 0; q < 2; ++q)
    aOff[q] = (size_t)(m0 + w * 32 + q * 16 + (l >> 2)) * IDIM + swzst;
  const size_t bOff = ((size_t)e * HDIM + n0 + w * 16 + (l >> 2)) * IDIM + swzst;

  f32x4 acc[2][4];
#pragma unroll
  for (int m = 0; m < 2; ++m)
#pragma unroll
    for (int nf = 0; nf < 4; ++nf) acc[m][nf] = (f32x4)0.f;

  auto stage = [&](int buf, int k0) {
#pragma unroll
    for (int q = 0; q < 2; ++q)
      gld16(act + aOff[q] + k0, &As[buf][(w * 32 + q * 16) * 32]);
    gld16(W2T + bOff + k0, &Bs[buf][(w * 16) * 32]);
  };

  stage(0, 0);
  __syncthreads();
  const int rslot = ((l >> 4) ^ ((l >> 1) & 3)) * 8;
  const int arow = (w * 32 + (l & 15)) * 32 + rslot;
  for (int t = 0; t < IDIM / 32; ++t) {
    const int cur = t & 1;
    if (t + 1 < IDIM / 32) stage(cur ^ 1, (t + 1) * 32);
    const bf16x8 a0 = *(const bf16x8*)&As[cur][arow];
    const bf16x8 a1 = *(const bf16x8*)&As[cur][arow + 16 * 32];
#pragma unroll
    for (int nf = 0; nf < 4; ++nf) {
      const bf16x8 b = *(const bf16x8*)&Bs[cur][(nf * 16 + (l & 15)) * 32 + rslot];
      acc[0][nf] = __builtin_amdgcn_mfma_f32_16x16x32_bf16(a0, b, acc[0][nf], 0, 0, 0);
      acc[1][nf] = __builtin_amdgcn_mfma_f32_16x16x32_bf16(a1, b, acc[1][nf], 0, 0, 0);
    }
    __syncthreads();
  }
  const int rbase = m0 + w * 32 + (l >> 4) * 4;
  const int cbase = n0 + (l & 15);
#pragma unroll
  for (int m = 0; m < 2; ++m)
#pragma unroll
    for (int nf = 0; nf < 4; ++nf)
#pragma unroll
      for (int r = 0; r < 4; ++r)
        so[(size_t)(rbase + m * 16 + r) * HDIM + cbase + nf * 16] = acc[m][nf][r];
}

__global__ void k_combine(const float* __restrict__ so, const int* __restrict__ pos,
                          const float* __restrict__ rw, float* __restrict__ out) {
  const int t = blockIdx.x, i = threadIdx.x;
  const int p0 = pos[2 * t], p1 = pos[2 * t + 1];
  const float w0 = rw[2 * t], w1 = rw[2 * t + 1];
  const float4 a = ((const float4*)(so + (size_t)p0 * HDIM))[i];
  const float4 b = ((const float4*)(so + (size_t)p1 * HDIM))[i];
  float4 o;
  o.x = w0 * a.x + w1 * b.x;
  o.y = w0 * a.y + w1 * b.y;
  o.z = w0 * a.z + w1 * b.z;
  o.w = w0 * a.w + w1 * b.w;
  ((float4*)(out + (size_t)t * HDIM))[i] = o;
}

extern "C" void kernel_launch(void* const* d_in, const int* in_sizes, int n_in,
                              void* d_out, int out_size, void* d_ws, size_t ws_size,
                              hipStream_t stream) {
  const float* x  = (const float*)d_in[0];
  const float* Wg = (const float*)d_in[1];
  const float* W1 = (const float*)d_in[2];
  const float* W2 = (const float*)d_in[3];   // (E, I, H)
  const float* W3 = (const float*)d_in[4];   // (E, H, I)
  float* out = (float*)d_out;
  char* ws = (char*)d_ws;
  int*   idx  = (int*)(ws + OFF_IDX);
  float* rw   = (float*)(ws + OFF_RW);
  int*   cnt  = (int*)(ws + OFF_CNT);
  int*   seg  = (int*)(ws + OFF_SEG);
  int*   rowsv= (int*)(ws + OFF_ROWS);
  int*   pos  = (int*)(ws + OFF_POS);
  unsigned short* xb  = (unsigned short*)(ws + OFF_XB);
  unsigned short* W1T = (unsigned short*)(ws + OFF_W1T);
  unsigned short* W3T = (unsigned short*)(ws + OFF_W3T);
  unsigned short* W2T = (unsigned short*)(ws + OFF_W2T);
  unsigned short* act = (unsigned short*)(ws + OFF_ACT);
  float* so = (float*)(ws + OFF_SO);

  k_init<<<20, 256, 0, stream>>>(cnt, rowsv);
  k_wt<<<dim3(IDIM / 64, HDIM / 64, NEXP), 256, 0, stream>>>(W1, W1T, HDIM, IDIM);
  k_wt<<<dim3(IDIM / 64, HDIM / 64, NEXP), 256, 0, stream>>>(W3, W3T, HDIM, IDIM);
  k_wt<<<dim3(HDIM / 64, IDIM / 64, NEXP), 256, 0, stream>>>(W2, W2T, IDIM, HDIM);
  k_router<<<NUM_TOK / 4, 256, 0, stream>>>(x, Wg, xb, idx, rw, cnt);
  k_seg<<<1, 1, 0, stream>>>(cnt, seg);
  k_scatter<<<NUM_TOK / 256, 256, 0, stream>>>(idx, seg, cnt + 8, rowsv, pos);
  k_gemm1<<<dim3(IDIM / 64, NTM), 256, 0, stream>>>(xb, W1T, W3T, seg, rowsv, act);
  k_gemm2<<<dim3(HDIM / 64, NTM), 256, 0, stream>>>(act, W2T, seg, so);
  k_combine<<<NUM_TOK, 256, 0, stream>>>(so, pos, rw, out);
}